// Round 8
// baseline (2662.471 us; speedup 1.0000x reference)
//
#include <hip/hip_runtime.h>
#include <cstdint>
#include <cmath>

#define S_LEN 1024
#define BATCH 64
#define IN_SZ 256
#define HID 512
#define OUT_SZ 256
#define WIH_LD 768  // W_ih leading dim = IN_SZ + HID
#define BH (BATCH * HID)            // 32768
#define XP_FLOATS (S_LEN * BH)      // 33,554,432 floats (128 MB)

// ============================ R8: MFMA recurrence ============================
// Evidence (R2-R7): the recurrence is VALU-issue-bound. v_dot2_f32_f16 is
// ~half-rate (~4cyc): 256 dot2/lane/step x 2 waves = ~2048 cyc/SIMD -- a hard
// floor for any vector-pipe formulation (R3/R5/R6/R7 all >= this wall).
// Fix: move the MACs to the MATRIX pipe. 4 WGs x 16 batches (MFMA M-tile):
//   D[out][batch] = Wh[512x512] x h[512x16per-WG]
//   per WG/step: 512 x mfma_f32_16x16x32_f16 = 64/wave (8 waves) ~ 640cyc/SIMD.
// Conventions anchored to the WORKING xproj_mfma kernel:
//   A-frag: lane&15 = M-row, k = ks*32 + (lane>>4)*8 + i  (8 f16, 16B contig)
//   B-frag: lane&15 = N-col, same k mapping (8 consecutive k of that column)
//   D:      col = lane&15, row = (lane>>4)*4 + reg        (m89-verified)
// Weight placement per wave (64 A-frags = 4 M-tiles x 16 K-tiles):
//   ks 0..2   -> streamed from L2 each step (12 frags, 96 KB/step/CU),
//               prefetched ONE STEP AHEAD (constant addresses)
//   ks 3..6   -> LDS (16 frags/wave, 128 KB total), golden lane*16B reads
//   ks 7..15  -> registers (36 frags = 144 VGPR/thread, step-invariant)
// h state: single 16 KB LDS buffer hbuf[ks][slot], slot = batch*4 + k_octet
//   (bijective lane->slot => conflict-free ds_read_b128 B-frags).
//   2 barriers/step (read-phase | write-phase) to allow single buffering.
#define NWG 4            // batch groups of 16
#define F_STR 3          // ks 0..2  streamed   (12 frags/wave)
#define F_LDS 4          // ks 3..6  LDS        (16 frags/wave)
#define F_REG 9          // ks 7..15 registers  (36 frags/wave)

// ws word layout after xp (wbase = ws + XP_FLOATS):
//  [0, 24576)          wAstr   (96 frags  = 6144 uint4)   dead after rnn
//  [24576, 98304)      wAreg   (288 frags = 18432 uint4)  dead after rnn
//  [98304, 131072)     wAlds   (128 frags = 8192 uint4)   dead after rnn
//  [131072, 196608)    wpk     (xproj B-fragments, 16384 uint4 = 256 KB)
//  overlays (used only after rnn completes):
//  [0, 65536)          sc_g[64][1024]
//  [65536, 98304)      ctx_g[64][512]

typedef _Float16 h2v __attribute__((ext_vector_type(2)));
typedef _Float16 f16x8 __attribute__((ext_vector_type(8)));
typedef float f32x4 __attribute__((ext_vector_type(4)));

// Branch-free tanh: 1 - 2/(e^{2x}+1). ~1e-6 abs err, exact limits. (R2 win.)
__device__ __forceinline__ float fast_tanh(float x) {
    float e = __expf(2.0f * x);
#if __has_builtin(__builtin_amdgcn_rcpf)
    float r = __builtin_amdgcn_rcpf(e + 1.0f);
#else
    float r = 1.0f / (e + 1.0f);
#endif
    return __builtin_fmaf(-2.0f, r, 1.0f);
}

__device__ __forceinline__ unsigned int pkf16(float a, float b) {
    return (unsigned int)__builtin_bit_cast(unsigned short, (_Float16)a) |
           ((unsigned int)__builtin_bit_cast(unsigned short, (_Float16)b) << 16);
}

// Pack Wh (W_ih[:, 256:768]) into per-destination A-fragment images.
// One thread per 16B fragment-slice: fid = mt*16 + ks, lane.
__global__ __launch_bounds__(256) void pack_wfrag(const float* __restrict__ W_ih,
                                                  uint4* __restrict__ wAstr,
                                                  uint4* __restrict__ wAreg,
                                                  uint4* __restrict__ wAlds) {
    int idx  = blockIdx.x * 256 + threadIdx.x;   // 0..32767
    int fid  = idx >> 6;                          // 0..511
    int lane = idx & 63;
    int mt   = fid >> 4;                          // M-tile 0..31  (out/16)
    int ks   = fid & 15;                          // K-tile 0..15  (in/32)
    int out  = mt * 16 + (lane & 15);
    int kin  = ks * 32 + (lane >> 4) * 8;
    const float* src = W_ih + (size_t)out * WIH_LD + IN_SZ + kin;
    union { uint4 u; _Float16 h[8]; } v;
#pragma unroll
    for (int i = 0; i < 8; ++i) v.h[i] = (_Float16)src[i];
    if (ks < F_STR)
        wAstr[(mt * F_STR + ks) * 64 + lane] = v.u;
    else if (ks < F_STR + F_LDS)
        wAlds[(mt * F_LDS + (ks - F_STR)) * 64 + lane] = v.u;
    else
        wAreg[(mt * F_REG + (ks - F_STR - F_LDS)) * 64 + lane] = v.u;
}

// Pack Wx (W_ih[:, 0:256]) into MFMA B-fragment layout, f16. (unchanged)
__global__ __launch_bounds__(256) void pack_wf16(const float* __restrict__ W_ih,
                                                 uint4* __restrict__ wpk) {
    int idx = blockIdx.x * 256 + threadIdx.x;   // 0..16383
    if (idx >= 16384) return;
    int nt   = idx >> 9;
    int ks   = (idx >> 6) & 7;
    int lane = idx & 63;
    int n  = nt * 16 + (lane & 15);
    int kb = ks * 32 + (lane >> 4) * 8;
    const float* src = W_ih + (size_t)n * WIH_LD + kb;
    union { uint4 u; _Float16 h[8]; } v;
#pragma unroll
    for (int i = 0; i < 8; ++i) v.h[i] = (_Float16)src[i];
    wpk[idx] = v.u;
}

// xp[s][b][h] = dot(x[b][s][:], Wx[h][:]) + b_ih[h], via f16 MFMA. (unchanged)
#define AH_LD 264   // 256 + 8-half pad
__global__ __launch_bounds__(256) void xproj_mfma(const float* __restrict__ x,
                                                  const uint4* __restrict__ wpk,
                                                  const float* __restrict__ b_ih,
                                                  float* __restrict__ xp) {
    const int s    = blockIdx.x;
    const int half = blockIdx.y;
    const int tid  = threadIdx.x;
    __shared__ __align__(16) _Float16 Ah[32 * AH_LD];
    __shared__ float bsh[HID];
    bsh[tid] = b_ih[tid];
    bsh[tid + 256] = b_ih[tid + 256];
    {
        int r  = tid >> 3;
        int c0 = (tid & 7) * 32;
        const float4* s4 = (const float4*)(x + ((size_t)(half * 32 + r) * S_LEN + s) * IN_SZ + c0);
        _Float16* dst = &Ah[r * AH_LD + c0];
#pragma unroll
        for (int i = 0; i < 8; ++i) {
            float4 v = s4[i];
            dst[4 * i + 0] = (_Float16)v.x;
            dst[4 * i + 1] = (_Float16)v.y;
            dst[4 * i + 2] = (_Float16)v.z;
            dst[4 * i + 3] = (_Float16)v.w;
        }
    }
    __syncthreads();
    const int lane = tid & 63;
    const int w    = tid >> 6;
    const int mt   = w & 1;
    const int ntb  = (w >> 1) * 16;
    f16x8 areg[8];
#pragma unroll
    for (int ks = 0; ks < 8; ++ks)
        areg[ks] = *(const f16x8*)&Ah[(mt * 16 + (lane & 15)) * AH_LD + ks * 32 + (lane >> 4) * 8];
    const int brow  = half * 32 + mt * 16 + (lane >> 4) * 4;
    const int ncol0 = lane & 15;
    for (int nt2 = 0; nt2 < 16; ++nt2) {
        int nt = ntb + nt2;
        const uint4* bp = wpk + (size_t)nt * 8 * 64 + lane;
        f32x4 acc = {0.f, 0.f, 0.f, 0.f};
#pragma unroll
        for (int ks = 0; ks < 8; ++ks) {
            uint4 bu = bp[ks * 64];
            acc = __builtin_amdgcn_mfma_f32_16x16x32_f16(
                areg[ks], __builtin_bit_cast(f16x8, bu), acc, 0, 0, 0);
        }
        int n = nt * 16 + ncol0;
        float bias = bsh[n];
        float* outp = xp + (size_t)s * BH + (size_t)brow * HID + n;
#pragma unroll
        for (int r = 0; r < 4; ++r) outp[(size_t)r * HID] = acc[r] + bias;
    }
}

// MFMA recurrence: 4 WGs x 512 thr (8 waves, 2/SIMD). WG g owns batches
// [16g, 16g+16). Wave w owns M-tiles (outs) 4w..4w+3.
__global__ __launch_bounds__(512, 2) void rnn_mfma(const uint4* __restrict__ wAstr,
                                                   const uint4* __restrict__ wAreg,
                                                   const uint4* __restrict__ wAlds,
                                                   float* __restrict__ xp) {
    const int g    = blockIdx.x;          // batch group 0..3
    const int t    = threadIdx.x;
    const int w    = t >> 6;              // wave 0..7
    const int lane = t & 63;
    const int c    = lane & 15;           // batch column
    const int q    = lane >> 4;           // k-octet / D row-quad

    __shared__ __align__(16) uint4 wlds[8 * 16 * 64];   // 128 KB A-frags (ks 3..6)
    __shared__ __align__(16) uint4 hbuf[16 * 64];       // 16 KB h f16 [ks][slot]

    // Register-resident A-frags: ks 7..15 (36 uint4 = 144 regs).
    uint4 wreg[4][F_REG];
#pragma unroll
    for (int m = 0; m < 4; ++m)
#pragma unroll
        for (int kr = 0; kr < F_REG; ++kr)
            wreg[m][kr] = wAreg[((size_t)((4 * w + m) * F_REG + kr)) * 64 + lane];

    // Stage LDS A-frags (linear copy; layout already kernel-order).
    for (int i = t; i < 8 * 16 * 64; i += 512) wlds[i] = wAlds[i];
    // h0 = 0.
    for (int i = t; i < 16 * 64; i += 512) { uint4 z = {0u, 0u, 0u, 0u}; hbuf[i] = z; }
    __syncthreads();

    const int slot = c * 4 + q;                          // bijective lane->slot
    const uint4* sbase = wAstr + (size_t)(12 * w) * 64 + lane;
    float* xcol = xp + (size_t)(16 * g + c) * HID + w * 64 + 4 * q;

    // Prologue: stream frags for s=0.
    uint4 sA[12];
#pragma unroll
    for (int i = 0; i < 12; ++i) sA[i] = sbase[(size_t)i * 64];

    for (int s = 0; s < S_LEN; ++s) {
        float* xps = xcol + (size_t)s * BH;
        f32x4 acc[4];
#pragma unroll
        for (int m = 0; m < 4; ++m) { f32x4 z = {0.f, 0.f, 0.f, 0.f}; acc[m] = z; }

        // Head: ks 0..2 (streamed A), ks 3..6 (LDS A).
#pragma unroll
        for (int ks = 0; ks < F_STR + F_LDS; ++ks) {
            uint4 Bf = hbuf[ks * 64 + slot];
#pragma unroll
            for (int m = 0; m < 4; ++m) {
                uint4 Af;
                if (ks < F_STR)
                    Af = sA[3 * m + ks];
                else
                    Af = wlds[(size_t)((16 * w + 4 * m + (ks - F_STR)) * 64 + lane)];
                acc[m] = __builtin_amdgcn_mfma_f32_16x16x32_f16(
                    __builtin_bit_cast(f16x8, Af), __builtin_bit_cast(f16x8, Bf),
                    acc[m], 0, 0, 0);
            }
        }

        // Mid: xp loads for this step + stream prefetch for s+1 (const addrs).
        float4 xq[4];
#pragma unroll
        for (int m = 0; m < 4; ++m) xq[m] = *(const float4*)(xps + m * 16);
#pragma unroll
        for (int i = 0; i < 12; ++i) sA[i] = sbase[(size_t)i * 64];

        // Tail: ks 7..15 (register A).
#pragma unroll
        for (int ks = F_STR + F_LDS; ks < 16; ++ks) {
            uint4 Bf = hbuf[ks * 64 + slot];
#pragma unroll
            for (int m = 0; m < 4; ++m)
                acc[m] = __builtin_amdgcn_mfma_f32_16x16x32_f16(
                    __builtin_bit_cast(f16x8, wreg[m][ks - F_STR - F_LDS]),
                    __builtin_bit_cast(f16x8, Bf), acc[m], 0, 0, 0);
        }

        // Barrier 1: all hbuf reads done before overwrite.
        asm volatile("s_waitcnt lgkmcnt(0)" ::: "memory");
        asm volatile("s_barrier" ::: "memory");

        // Epilogue: tanh, store hidden (f32), write h f16 into hbuf.
#pragma unroll
        for (int m = 0; m < 4; ++m) {
            float4 v;
            v.x = fast_tanh(acc[m][0] + xq[m].x);
            v.y = fast_tanh(acc[m][1] + xq[m].y);
            v.z = fast_tanh(acc[m][2] + xq[m].z);
            v.w = fast_tanh(acc[m][3] + xq[m].w);
            *(float4*)(xps + m * 16) = v;                  // hidden_seq (fp32)
            int g0   = (4 * w + m) * 16 + 4 * q;           // first out of this quad
            int ksh  = g0 >> 5;
            int sh   = (g0 >> 3) & 3;
            int half = (g0 >> 2) & 1;
            uint2 pk;
            pk.x = pkf16(v.x, v.y);
            pk.y = pkf16(v.z, v.w);
            *(uint2*)((char*)&hbuf[ksh * 64 + c * 4 + sh] + half * 8) = pk;
        }

        // Barrier 2: h writes visible before next step's reads.
        asm volatile("s_waitcnt lgkmcnt(0)" ::: "memory");
        asm volatile("s_barrier" ::: "memory");
    }
}

// scores: sc_g[b][s] = dot(hbuf[s][b][:], hbuf[S-1][b][:]). (unchanged)
__global__ __launch_bounds__(256) void attn_sc(const float* __restrict__ hbuf,
                                               float* __restrict__ sc_g) {
    const int b     = blockIdx.x;
    const int chunk = blockIdx.y;
    const int tid   = threadIdx.x;
    const int lane  = tid & 63;
    const int wv    = tid >> 6;
    __shared__ float fh[HID];
    fh[tid] = hbuf[(size_t)(S_LEN - 1) * BH + (size_t)b * HID + tid];
    fh[tid + 256] = hbuf[(size_t)(S_LEN - 1) * BH + (size_t)b * HID + tid + 256];
    __syncthreads();
    float4 f0 = *(const float4*)&fh[lane * 8];
    float4 f1 = *(const float4*)&fh[lane * 8 + 4];
    for (int i = 0; i < 32; ++i) {
        int s = chunk * 128 + wv * 32 + i;
        const float* hr = hbuf + (size_t)s * BH + (size_t)b * HID + lane * 8;
        float4 a0 = *(const float4*)hr;
        float4 a1 = *(const float4*)(hr + 4);
        float p = a0.x * f0.x + a0.y * f0.y + a0.z * f0.z + a0.w * f0.w +
                  a1.x * f1.x + a1.y * f1.y + a1.z * f1.z + a1.w * f1.w;
#pragma unroll
        for (int off = 32; off; off >>= 1) p += __shfl_down(p, off, 64);
        if (lane == 0) sc_g[(size_t)b * S_LEN + s] = p;
    }
}

// softmax (redundant per h-chunk) + context. (unchanged)
__global__ __launch_bounds__(256) void attn_ctx(const float* __restrict__ hbuf,
                                                const float* __restrict__ sc_g,
                                                float* __restrict__ ctx_g) {
    const int b   = blockIdx.x;
    const int hc  = blockIdx.y * 128;
    const int tid = threadIdx.x;
    const int lane = tid & 63;
    const int wv   = tid >> 6;
    __shared__ float sc[S_LEN];
    __shared__ float red[4];
    __shared__ float part[256];
    for (int i = tid; i < S_LEN; i += 256) sc[i] = sc_g[(size_t)b * S_LEN + i];
    __syncthreads();
    float m = -1e30f;
    for (int i = tid; i < S_LEN; i += 256) m = fmaxf(m, sc[i]);
#pragma unroll
    for (int off = 32; off; off >>= 1) m = fmaxf(m, __shfl_down(m, off, 64));
    if (lane == 0) red[wv] = m;
    __syncthreads();
    m = fmaxf(fmaxf(red[0], red[1]), fmaxf(red[2], red[3]));
    float sum = 0.f;
    for (int i = tid; i < S_LEN; i += 256) {
        float e = __expf(sc[i] - m);
        sc[i] = e;
        sum += e;
    }
#pragma unroll
    for (int off = 32; off; off >>= 1) sum += __shfl_down(sum, off, 64);
    __syncthreads();
    if (lane == 0) red[wv] = sum;
    __syncthreads();
    float inv = 1.f / (red[0] + red[1] + red[2] + red[3]);
    const int h  = hc + (tid & 127);
    const int sh = tid >> 7;
    const float* hp = hbuf + (size_t)sh * 512 * BH + (size_t)b * HID + h;
    float c = 0.f;
#pragma unroll 4
    for (int s2 = 0; s2 < 512; ++s2)
        c += sc[sh * 512 + s2] * hp[(size_t)s2 * BH];
    part[tid] = c;
    __syncthreads();
    if (tid < 128) ctx_g[(size_t)b * HID + hc + tid] = (part[tid] + part[tid + 128]) * inv;
}

// out[b][o] = b_ho[o] + dot(ctx_g[b][:], W_ho[o][:]). (unchanged)
__global__ __launch_bounds__(256) void attn_fin(const float* __restrict__ ctx_g,
                                                const float* __restrict__ W_ho,
                                                const float* __restrict__ b_ho,
                                                float* __restrict__ out) {
    const int b   = blockIdx.x;
    const int tid = threadIdx.x;
    __shared__ float ctx[HID];
    ctx[tid] = ctx_g[(size_t)b * HID + tid];
    ctx[tid + 256] = ctx_g[(size_t)b * HID + tid + 256];
    __syncthreads();
    float o = b_ho[tid];
    const float* wr = W_ho + (size_t)tid * HID;
#pragma unroll 4
    for (int k = 0; k < HID; ++k) o += wr[k] * ctx[k];
    out[(size_t)b * OUT_SZ + tid] = o;
}

extern "C" void kernel_launch(void* const* d_in, const int* in_sizes, int n_in,
                              void* d_out, int out_size, void* d_ws, size_t ws_size,
                              hipStream_t stream) {
    const float* x    = (const float*)d_in[0];
    const float* W_ih = (const float*)d_in[1];
    const float* b_ih = (const float*)d_in[2];
    const float* W_ho = (const float*)d_in[3];
    const float* b_ho = (const float*)d_in[4];
    float* out = (float*)d_out;
    float* ws  = (float*)d_ws;

    float* xp = ws;
    unsigned int* wbase = (unsigned int*)(ws + XP_FLOATS);
    uint4* wAstr = (uint4*)wbase;                     // [0, 24576) words
    uint4* wAreg = (uint4*)(wbase + 24576);           // [24576, 98304)
    uint4* wAlds = (uint4*)(wbase + 98304);           // [98304, 131072)
    uint4* wpk   = (uint4*)(wbase + 131072);          // [131072, 196608)
    float* sc_g  = (float*)wbase;                     // overlay, post-rnn
    float* ctx_g = (float*)(wbase + 65536);           // overlay, post-rnn

    pack_wfrag<<<dim3(128), dim3(256), 0, stream>>>(W_ih, wAstr, wAreg, wAlds);
    pack_wf16<<<dim3(64), dim3(256), 0, stream>>>(W_ih, wpk);
    xproj_mfma<<<dim3(1024, 2), dim3(256), 0, stream>>>(x, wpk, b_ih, xp);
    rnn_mfma<<<dim3(NWG), dim3(512), 0, stream>>>(wAstr, wAreg, wAlds, xp);
    attn_sc<<<dim3(64, 8), dim3(256), 0, stream>>>(xp, sc_g);
    attn_ctx<<<dim3(64, 4), dim3(256), 0, stream>>>(xp, sc_g, ctx_g);
    attn_fin<<<dim3(64), dim3(256), 0, stream>>>(ctx_g, W_ho, b_ho, out);
}

// Round 9
// 2596.336 us; speedup vs baseline: 1.0255x; 1.0255x over previous
//
#include <hip/hip_runtime.h>
#include <cstdint>
#include <cmath>

#define S_LEN 1024
#define BATCH 64
#define IN_SZ 256
#define HID 512
#define OUT_SZ 256
#define WIH_LD 768  // W_ih leading dim = IN_SZ + HID
#define BH (BATCH * HID)            // 32768
#define XP_FLOATS (S_LEN * BH)      // 33,554,432 floats (128 MB)

// ============================ R9: MFMA recurrence ============================
// R8 proved the MFMA formulation (passed, absmax 0.0078) at 5714 cyc/step.
// R9 keeps the verified fragment conventions EXACTLY and fixes three leaks:
//  (a) hbuf lane-order layout: B-frag at hbuf[ks*64 + lane] -> reads stride
//      16B sequential (conflict-free); epilogue writes stride 16B per phase
//      (conflict-free). R8's slot=c*4+q cost 5.77e6 conflict cycles.
//  (b) sA is step-invariant and permanently live in 48 VGPRs -> the per-step
//      reload from L2 (96 KB/step) was pure waste. Load ONCE in prologue.
//  (c) xp loads issued at TOP of step (addresses depend only on s) -> ~full
//      compute phase (>1500 cyc) covers the ~900 cyc HBM latency.
// Conventions (verified by R8 pass):
//   A-frag: lane&15 = M-row, k = ks*32 + (lane>>4)*8 + i  (8 f16, 16B contig)
//   B-frag: lane&15 = N-col (batch), same k mapping
//   D:      col = lane&15, row = (lane>>4)*4 + reg
// Weight placement per wave (64 A-frags = 4 M-tiles x 16 K-tiles):
//   ks 0..2   -> VGPR-resident (12 frags, 48 regs; was "streamed" in R8)
//   ks 3..6   -> LDS (16 frags/wave, 128 KB total), lane*16B reads
//   ks 7..15  -> registers (36 frags = 144 reg words, AGPR-allocated)
// h state: single 16 KB LDS buffer hbuf[ks][lane]; 2 barriers/step.
#define NWG 4            // batch groups of 16
#define F_STR 3          // ks 0..2  reg (prologue-loaded)
#define F_LDS 4          // ks 3..6  LDS
#define F_REG 9          // ks 7..15 reg

// ws word layout after xp (wbase = ws + XP_FLOATS):
//  [0, 24576)          wAstr   (96 frags  = 6144 uint4)   dead after rnn
//  [24576, 98304)      wAreg   (288 frags = 18432 uint4)  dead after rnn
//  [98304, 131072)     wAlds   (128 frags = 8192 uint4)   dead after rnn
//  [131072, 196608)    wpk     (xproj B-fragments, 16384 uint4 = 256 KB)
//  overlays (used only after rnn completes):
//  [0, 65536)          sc_g[64][1024]
//  [65536, 98304)      ctx_g[64][512]

typedef _Float16 h2v __attribute__((ext_vector_type(2)));
typedef _Float16 f16x8 __attribute__((ext_vector_type(8)));
typedef float f32x4 __attribute__((ext_vector_type(4)));

// Branch-free tanh: 1 - 2/(e^{2x}+1). ~1e-6 abs err, exact limits. (R2 win.)
__device__ __forceinline__ float fast_tanh(float x) {
    float e = __expf(2.0f * x);
#if __has_builtin(__builtin_amdgcn_rcpf)
    float r = __builtin_amdgcn_rcpf(e + 1.0f);
#else
    float r = 1.0f / (e + 1.0f);
#endif
    return __builtin_fmaf(-2.0f, r, 1.0f);
}

__device__ __forceinline__ unsigned int pkf16(float a, float b) {
    return (unsigned int)__builtin_bit_cast(unsigned short, (_Float16)a) |
           ((unsigned int)__builtin_bit_cast(unsigned short, (_Float16)b) << 16);
}

// Pack Wh (W_ih[:, 256:768]) into per-destination A-fragment images. (= R8)
__global__ __launch_bounds__(256) void pack_wfrag(const float* __restrict__ W_ih,
                                                  uint4* __restrict__ wAstr,
                                                  uint4* __restrict__ wAreg,
                                                  uint4* __restrict__ wAlds) {
    int idx  = blockIdx.x * 256 + threadIdx.x;   // 0..32767
    int fid  = idx >> 6;                          // 0..511
    int lane = idx & 63;
    int mt   = fid >> 4;                          // M-tile 0..31  (out/16)
    int ks   = fid & 15;                          // K-tile 0..15  (in/32)
    int out  = mt * 16 + (lane & 15);
    int kin  = ks * 32 + (lane >> 4) * 8;
    const float* src = W_ih + (size_t)out * WIH_LD + IN_SZ + kin;
    union { uint4 u; _Float16 h[8]; } v;
#pragma unroll
    for (int i = 0; i < 8; ++i) v.h[i] = (_Float16)src[i];
    if (ks < F_STR)
        wAstr[(mt * F_STR + ks) * 64 + lane] = v.u;
    else if (ks < F_STR + F_LDS)
        wAlds[(mt * F_LDS + (ks - F_STR)) * 64 + lane] = v.u;
    else
        wAreg[(mt * F_REG + (ks - F_STR - F_LDS)) * 64 + lane] = v.u;
}

// Pack Wx (W_ih[:, 0:256]) into MFMA B-fragment layout, f16. (unchanged)
__global__ __launch_bounds__(256) void pack_wf16(const float* __restrict__ W_ih,
                                                 uint4* __restrict__ wpk) {
    int idx = blockIdx.x * 256 + threadIdx.x;   // 0..16383
    if (idx >= 16384) return;
    int nt   = idx >> 9;
    int ks   = (idx >> 6) & 7;
    int lane = idx & 63;
    int n  = nt * 16 + (lane & 15);
    int kb = ks * 32 + (lane >> 4) * 8;
    const float* src = W_ih + (size_t)n * WIH_LD + kb;
    union { uint4 u; _Float16 h[8]; } v;
#pragma unroll
    for (int i = 0; i < 8; ++i) v.h[i] = (_Float16)src[i];
    wpk[idx] = v.u;
}

// xp[s][b][h] = dot(x[b][s][:], Wx[h][:]) + b_ih[h], via f16 MFMA. (unchanged)
#define AH_LD 264   // 256 + 8-half pad
__global__ __launch_bounds__(256) void xproj_mfma(const float* __restrict__ x,
                                                  const uint4* __restrict__ wpk,
                                                  const float* __restrict__ b_ih,
                                                  float* __restrict__ xp) {
    const int s    = blockIdx.x;
    const int half = blockIdx.y;
    const int tid  = threadIdx.x;
    __shared__ __align__(16) _Float16 Ah[32 * AH_LD];
    __shared__ float bsh[HID];
    bsh[tid] = b_ih[tid];
    bsh[tid + 256] = b_ih[tid + 256];
    {
        int r  = tid >> 3;
        int c0 = (tid & 7) * 32;
        const float4* s4 = (const float4*)(x + ((size_t)(half * 32 + r) * S_LEN + s) * IN_SZ + c0);
        _Float16* dst = &Ah[r * AH_LD + c0];
#pragma unroll
        for (int i = 0; i < 8; ++i) {
            float4 v = s4[i];
            dst[4 * i + 0] = (_Float16)v.x;
            dst[4 * i + 1] = (_Float16)v.y;
            dst[4 * i + 2] = (_Float16)v.z;
            dst[4 * i + 3] = (_Float16)v.w;
        }
    }
    __syncthreads();
    const int lane = tid & 63;
    const int w    = tid >> 6;
    const int mt   = w & 1;
    const int ntb  = (w >> 1) * 16;
    f16x8 areg[8];
#pragma unroll
    for (int ks = 0; ks < 8; ++ks)
        areg[ks] = *(const f16x8*)&Ah[(mt * 16 + (lane & 15)) * AH_LD + ks * 32 + (lane >> 4) * 8];
    const int brow  = half * 32 + mt * 16 + (lane >> 4) * 4;
    const int ncol0 = lane & 15;
    for (int nt2 = 0; nt2 < 16; ++nt2) {
        int nt = ntb + nt2;
        const uint4* bp = wpk + (size_t)nt * 8 * 64 + lane;
        f32x4 acc = {0.f, 0.f, 0.f, 0.f};
#pragma unroll
        for (int ks = 0; ks < 8; ++ks) {
            uint4 bu = bp[ks * 64];
            acc = __builtin_amdgcn_mfma_f32_16x16x32_f16(
                areg[ks], __builtin_bit_cast(f16x8, bu), acc, 0, 0, 0);
        }
        int n = nt * 16 + ncol0;
        float bias = bsh[n];
        float* outp = xp + (size_t)s * BH + (size_t)brow * HID + n;
#pragma unroll
        for (int r = 0; r < 4; ++r) outp[(size_t)r * HID] = acc[r] + bias;
    }
}

// MFMA recurrence: 4 WGs x 512 thr (8 waves, 2/SIMD). WG g owns batches
// [16g, 16g+16). Wave w owns M-tiles (outs) 4w..4w+3.
__global__ __launch_bounds__(512, 2) void rnn_mfma(const uint4* __restrict__ wAstr,
                                                   const uint4* __restrict__ wAreg,
                                                   const uint4* __restrict__ wAlds,
                                                   float* __restrict__ xp) {
    const int g    = blockIdx.x;          // batch group 0..3
    const int t    = threadIdx.x;
    const int w    = t >> 6;              // wave 0..7
    const int lane = t & 63;
    const int c    = lane & 15;           // batch column
    const int q    = lane >> 4;           // k-octet / D row-quad

    __shared__ __align__(16) uint4 wlds[8 * 16 * 64];   // 128 KB A-frags (ks 3..6)
    __shared__ __align__(16) uint4 hbuf[16 * 64];       // 16 KB h f16, LANE-order

    // Register-resident A-frags: ks 7..15 (36 uint4, AGPR-allocated).
    uint4 wreg[4][F_REG];
#pragma unroll
    for (int m = 0; m < 4; ++m)
#pragma unroll
        for (int kr = 0; kr < F_REG; ++kr)
            wreg[m][kr] = wAreg[((size_t)((4 * w + m) * F_REG + kr)) * 64 + lane];

    // ks 0..2 A-frags: loaded ONCE (step-invariant; R8 wastefully reloaded
    // these from L2 every step at the same addresses).
    uint4 sA[12];
    {
        const uint4* sbase = wAstr + (size_t)(12 * w) * 64 + lane;
#pragma unroll
        for (int i = 0; i < 12; ++i) sA[i] = sbase[(size_t)i * 64];
    }

    // Stage LDS A-frags (linear copy; layout already kernel-order).
    for (int i = t; i < 8 * 16 * 64; i += 512) wlds[i] = wAlds[i];
    // h0 = 0.
    for (int i = t; i < 16 * 64; i += 512) { uint4 z = {0u, 0u, 0u, 0u}; hbuf[i] = z; }
    __syncthreads();

    float* xcol = xp + (size_t)(16 * g + c) * HID + w * 64 + 4 * q;
    // Epilogue write target (lane-order hbuf), per-m constants:
    //   g0 = (4w+m)*16 + 4q; o = g0>>3; frag(ks_d=o>>2, lane_d=(o&3)*16+c),
    //   byte offset (q&1)*8. Within a 16-lane phase: stride 16B (no conflicts).

    for (int s = 0; s < S_LEN; ++s) {
        float* xps = xcol + (size_t)s * BH;

        // Top-of-step: issue this step's xp loads (HBM ~900cyc hidden under
        // the whole compute phase).
        float4 xq[4];
#pragma unroll
        for (int m = 0; m < 4; ++m) xq[m] = *(const float4*)(xps + m * 16);

        f32x4 acc[4];
#pragma unroll
        for (int m = 0; m < 4; ++m) { f32x4 z = {0.f, 0.f, 0.f, 0.f}; acc[m] = z; }

        // Head: ks 0..2 (reg sA), ks 3..6 (LDS A). B-frag read: lane*16B.
#pragma unroll
        for (int ks = 0; ks < F_STR + F_LDS; ++ks) {
            uint4 Bf = hbuf[ks * 64 + lane];
#pragma unroll
            for (int m = 0; m < 4; ++m) {
                uint4 Af;
                if (ks < F_STR)
                    Af = sA[3 * m + ks];
                else
                    Af = wlds[(size_t)((16 * w + 4 * m + (ks - F_STR)) * 64 + lane)];
                acc[m] = __builtin_amdgcn_mfma_f32_16x16x32_f16(
                    __builtin_bit_cast(f16x8, Af), __builtin_bit_cast(f16x8, Bf),
                    acc[m], 0, 0, 0);
            }
        }

        // Tail: ks 7..15 (register A).
#pragma unroll
        for (int ks = F_STR + F_LDS; ks < 16; ++ks) {
            uint4 Bf = hbuf[ks * 64 + lane];
#pragma unroll
            for (int m = 0; m < 4; ++m)
                acc[m] = __builtin_amdgcn_mfma_f32_16x16x32_f16(
                    __builtin_bit_cast(f16x8, wreg[m][ks - F_STR - F_LDS]),
                    __builtin_bit_cast(f16x8, Bf), acc[m], 0, 0, 0);
        }

        // Barrier 1: all hbuf reads done before overwrite.
        asm volatile("s_waitcnt lgkmcnt(0)" ::: "memory");
        asm volatile("s_barrier" ::: "memory");

        // Epilogue: tanh, store hidden (f32), write h f16 into hbuf (lane-order).
#pragma unroll
        for (int m = 0; m < 4; ++m) {
            float4 v;
            v.x = fast_tanh(acc[m][0] + xq[m].x);
            v.y = fast_tanh(acc[m][1] + xq[m].y);
            v.z = fast_tanh(acc[m][2] + xq[m].z);
            v.w = fast_tanh(acc[m][3] + xq[m].w);
            *(float4*)(xps + m * 16) = v;                  // hidden_seq (fp32)
            int g0   = (4 * w + m) * 16 + 4 * q;           // first out of this quad
            int o    = g0 >> 3;                            // k-octet
            int ks_d = o >> 2;
            int q_d  = o & 3;
            uint2 pk;
            pk.x = pkf16(v.x, v.y);
            pk.y = pkf16(v.z, v.w);
            *(uint2*)((char*)&hbuf[ks_d * 64 + q_d * 16 + c] + (q & 1) * 8) = pk;
        }

        // Barrier 2: h writes visible before next step's reads.
        asm volatile("s_waitcnt lgkmcnt(0)" ::: "memory");
        asm volatile("s_barrier" ::: "memory");
    }
}

// scores: sc_g[b][s] = dot(hbuf[s][b][:], hbuf[S-1][b][:]). (unchanged)
__global__ __launch_bounds__(256) void attn_sc(const float* __restrict__ hbuf,
                                               float* __restrict__ sc_g) {
    const int b     = blockIdx.x;
    const int chunk = blockIdx.y;
    const int tid   = threadIdx.x;
    const int lane  = tid & 63;
    const int wv    = tid >> 6;
    __shared__ float fh[HID];
    fh[tid] = hbuf[(size_t)(S_LEN - 1) * BH + (size_t)b * HID + tid];
    fh[tid + 256] = hbuf[(size_t)(S_LEN - 1) * BH + (size_t)b * HID + tid + 256];
    __syncthreads();
    float4 f0 = *(const float4*)&fh[lane * 8];
    float4 f1 = *(const float4*)&fh[lane * 8 + 4];
    for (int i = 0; i < 32; ++i) {
        int s = chunk * 128 + wv * 32 + i;
        const float* hr = hbuf + (size_t)s * BH + (size_t)b * HID + lane * 8;
        float4 a0 = *(const float4*)hr;
        float4 a1 = *(const float4*)(hr + 4);
        float p = a0.x * f0.x + a0.y * f0.y + a0.z * f0.z + a0.w * f0.w +
                  a1.x * f1.x + a1.y * f1.y + a1.z * f1.z + a1.w * f1.w;
#pragma unroll
        for (int off = 32; off; off >>= 1) p += __shfl_down(p, off, 64);
        if (lane == 0) sc_g[(size_t)b * S_LEN + s] = p;
    }
}

// softmax (redundant per h-chunk) + context. (unchanged)
__global__ __launch_bounds__(256) void attn_ctx(const float* __restrict__ hbuf,
                                                const float* __restrict__ sc_g,
                                                float* __restrict__ ctx_g) {
    const int b   = blockIdx.x;
    const int hc  = blockIdx.y * 128;
    const int tid = threadIdx.x;
    const int lane = tid & 63;
    const int wv   = tid >> 6;
    __shared__ float sc[S_LEN];
    __shared__ float red[4];
    __shared__ float part[256];
    for (int i = tid; i < S_LEN; i += 256) sc[i] = sc_g[(size_t)b * S_LEN + i];
    __syncthreads();
    float m = -1e30f;
    for (int i = tid; i < S_LEN; i += 256) m = fmaxf(m, sc[i]);
#pragma unroll
    for (int off = 32; off; off >>= 1) m = fmaxf(m, __shfl_down(m, off, 64));
    if (lane == 0) red[wv] = m;
    __syncthreads();
    m = fmaxf(fmaxf(red[0], red[1]), fmaxf(red[2], red[3]));
    float sum = 0.f;
    for (int i = tid; i < S_LEN; i += 256) {
        float e = __expf(sc[i] - m);
        sc[i] = e;
        sum += e;
    }
#pragma unroll
    for (int off = 32; off; off >>= 1) sum += __shfl_down(sum, off, 64);
    __syncthreads();
    if (lane == 0) red[wv] = sum;
    __syncthreads();
    float inv = 1.f / (red[0] + red[1] + red[2] + red[3]);
    const int h  = hc + (tid & 127);
    const int sh = tid >> 7;
    const float* hp = hbuf + (size_t)sh * 512 * BH + (size_t)b * HID + h;
    float c = 0.f;
#pragma unroll 4
    for (int s2 = 0; s2 < 512; ++s2)
        c += sc[sh * 512 + s2] * hp[(size_t)s2 * BH];
    part[tid] = c;
    __syncthreads();
    if (tid < 128) ctx_g[(size_t)b * HID + hc + tid] = (part[tid] + part[tid + 128]) * inv;
}

// out[b][o] = b_ho[o] + dot(ctx_g[b][:], W_ho[o][:]). (unchanged)
__global__ __launch_bounds__(256) void attn_fin(const float* __restrict__ ctx_g,
                                                const float* __restrict__ W_ho,
                                                const float* __restrict__ b_ho,
                                                float* __restrict__ out) {
    const int b   = blockIdx.x;
    const int tid = threadIdx.x;
    __shared__ float ctx[HID];
    ctx[tid] = ctx_g[(size_t)b * HID + tid];
    ctx[tid + 256] = ctx_g[(size_t)b * HID + tid + 256];
    __syncthreads();
    float o = b_ho[tid];
    const float* wr = W_ho + (size_t)tid * HID;
#pragma unroll 4
    for (int k = 0; k < HID; ++k) o += wr[k] * ctx[k];
    out[(size_t)b * OUT_SZ + tid] = o;
}

extern "C" void kernel_launch(void* const* d_in, const int* in_sizes, int n_in,
                              void* d_out, int out_size, void* d_ws, size_t ws_size,
                              hipStream_t stream) {
    const float* x    = (const float*)d_in[0];
    const float* W_ih = (const float*)d_in[1];
    const float* b_ih = (const float*)d_in[2];
    const float* W_ho = (const float*)d_in[3];
    const float* b_ho = (const float*)d_in[4];
    float* out = (float*)d_out;
    float* ws  = (float*)d_ws;

    float* xp = ws;
    unsigned int* wbase = (unsigned int*)(ws + XP_FLOATS);
    uint4* wAstr = (uint4*)wbase;                     // [0, 24576) words
    uint4* wAreg = (uint4*)(wbase + 24576);           // [24576, 98304)
    uint4* wAlds = (uint4*)(wbase + 98304);           // [98304, 131072)
    uint4* wpk   = (uint4*)(wbase + 131072);          // [131072, 196608)
    float* sc_g  = (float*)wbase;                     // overlay, post-rnn
    float* ctx_g = (float*)(wbase + 65536);           // overlay, post-rnn

    pack_wfrag<<<dim3(128), dim3(256), 0, stream>>>(W_ih, wAstr, wAreg, wAlds);
    pack_wf16<<<dim3(64), dim3(256), 0, stream>>>(W_ih, wpk);
    xproj_mfma<<<dim3(1024, 2), dim3(256), 0, stream>>>(x, wpk, b_ih, xp);
    rnn_mfma<<<dim3(NWG), dim3(512), 0, stream>>>(wAstr, wAreg, wAlds, xp);
    attn_sc<<<dim3(64, 8), dim3(256), 0, stream>>>(xp, sc_g);
    attn_ctx<<<dim3(64, 4), dim3(256), 0, stream>>>(xp, sc_g, ctx_g);
    attn_fin<<<dim3(64), dim3(256), 0, stream>>>(ctx_g, W_ho, b_ho, out);
}